// Round 10
// baseline (41.779 us; speedup 1.0000x reference)
//
#include <hip/hip_runtime.h>
#include <hip/hip_bf16.h>

typedef __attribute__((ext_vector_type(8))) short short8;
typedef __attribute__((ext_vector_type(2))) float f32x2;
typedef __attribute__((ext_vector_type(4))) float f32x4;
typedef __attribute__((ext_vector_type(16))) float f32x16;

#define NROWS 65536             // BATCH * N_EDGES
#define EDGE_DIM 64
#define NODE_DIM 32
#define NN 1024                 // NODE_DIM^2

__device__ __forceinline__ short f2bf(float f) {
    unsigned u = __builtin_bit_cast(unsigned, f);
    u += 0x7FFFu + ((u >> 16) & 1u);            // round-to-nearest-even
    return (short)(u >> 16);
}

// Pack W [64,1024] f32 -> bf16 A-operand fragments for mfma_f32_32x32x16_bf16.
// frag id = i*4 + ks (i = output row 0..31, ks = K-step 0..3).
// Wb[(frag*64 + l)*8 + t] = bf16(W[ks*16 + (l>>5)*8 + t, i*32 + (l&31)])
// (verified correct R2..R9)
__global__ void prep_W(const float* __restrict__ W, short* __restrict__ Wb) {
    int frag = blockIdx.x;            // 128 blocks x 1 wave
    int l = threadIdx.x;              // 0..63
    int col = (frag >> 2) * 32 + (l & 31);
    int fb = (frag & 3) * 16 + ((l >> 5) * 8);
    short8 v;
#pragma unroll
    for (int t = 0; t < 8; ++t)
        v[t] = f2bf(W[(size_t)(fb + t) * NN + col]);
    *reinterpret_cast<short8*>(Wb + ((size_t)frag * 64 + l) * 8) = v;
}

// 256 blocks x 1024 threads (16 waves) x 256 edges/block. Inverted R7:
// W in REGISTERS (wave w owns i = 2w, 2w+1 -> 8 frags = 32 VGPR, coalesced
// from packed Wb), edges bf16-staged in 32 KB LDS (one barrier). Per 32-edge
// group: 4 conflict-free ds_read_b128 (shared ef) + node dwordx4 (L1-hot,
// same addrs all waves) + per-i {bias C-init, 4-chain mfma_32x32x16,
// relu+matvec epilogue (4 indep partials), shfl_xor(32), float2 store}.
// DS traffic 2 reads/edge (half of R7); 4 waves/SIMD (launch_bounds(1024,1)
// -> 128 VGPR cap, est. ~118 used, no spill).
__global__ __launch_bounds__(1024, 1) void mp_main(
    const float* __restrict__ node, const float* __restrict__ edge,
    const short* __restrict__ Wb, const float* __restrict__ bias,
    float* __restrict__ out) {
    // ldsE[eg(8)][ks(4)][lane(64)][8 shorts] = 2048 entries x 16 B = 32 KB
    __shared__ __align__(16) short ldsE[16384];

    const int tid = threadIdx.x;
    const int wid = tid >> 6;                 // 0..15 -> i-pair {2w, 2w+1}
    const int l   = tid & 63;
    const int e32 = l & 31;                   // lane's edge col (MFMA N)
    const int h   = l >> 5;                   // lane half (k-group / row offset)
    const int eb  = blockIdx.x * 256;         // block's first edge row

    // ---- W fragments for this wave's 2 i's -> 32 VGPR (coalesced, one-time)
    short8 wfr[2][4];
#pragma unroll
    for (int il = 0; il < 2; ++il)
#pragma unroll
        for (int ks = 0; ks < 4; ++ks) {
            int frag = (wid * 2 + il) * 4 + ks;
            wfr[il][ks] = *reinterpret_cast<const short8*>(
                Wb + ((size_t)frag * 64 + l) * 8);
        }

    // ---- stage edge fragments: 2048 entries, 2 per thread (cvt to bf16) ----
#pragma unroll
    for (int k = 0; k < 2; ++k) {
        int n = k * 1024 + tid;               // entry id
        int le = n & 63;                      // entry lane
        int ks = (n >> 6) & 3;
        int eg = n >> 8;
        const float* erow = edge + (size_t)(eb + eg * 32 + (le & 31)) * EDGE_DIM
                                 + ks * 16 + (le >> 5) * 8;
        f32x4 a = *reinterpret_cast<const f32x4*>(erow);
        f32x4 b = *reinterpret_cast<const f32x4*>(erow + 4);
        short8 v;
        v[0] = f2bf(a[0]); v[1] = f2bf(a[1]); v[2] = f2bf(a[2]); v[3] = f2bf(a[3]);
        v[4] = f2bf(b[0]); v[5] = f2bf(b[1]); v[6] = f2bf(b[2]); v[7] = f2bf(b[3]);
        *reinterpret_cast<short8*>(&ldsE[n * 8]) = v;
    }
    __syncthreads();                          // the ONLY barrier

#pragma unroll 2
    for (int eg = 0; eg < 8; ++eg) {
        // shared edge B-fragments for this 32-edge group (conflict-free)
        short8 ef0 = *reinterpret_cast<const short8*>(&ldsE[((eg * 4 + 0) * 64 + l) * 8]);
        short8 ef1 = *reinterpret_cast<const short8*>(&ldsE[((eg * 4 + 1) * 64 + l) * 8]);
        short8 ef2 = *reinterpret_cast<const short8*>(&ldsE[((eg * 4 + 2) * 64 + l) * 8]);
        short8 ef3 = *reinterpret_cast<const short8*>(&ldsE[((eg * 4 + 3) * 64 + l) * 8]);

        // node values: acc reg r=q*4+rr -> j = q*8 + h*4 + rr (L1-hot)
        const float* nrow = node + (size_t)(eb + eg * 32 + e32) * NODE_DIM;
        f32x4 n0 = *reinterpret_cast<const f32x4*>(nrow + 0 * 8 + h * 4);
        f32x4 n1 = *reinterpret_cast<const f32x4*>(nrow + 1 * 8 + h * 4);
        f32x4 n2 = *reinterpret_cast<const f32x4*>(nrow + 2 * 8 + h * 4);
        f32x4 n3 = *reinterpret_cast<const f32x4*>(nrow + 3 * 8 + h * 4);

        f32x2 vq;
#pragma unroll
        for (int il = 0; il < 2; ++il) {
            const int i = wid * 2 + il;
            // bias as C-init: reg q*4+rr -> row q*8 + h*4 + rr (L1-hot)
            f32x16 acc;
#pragma unroll
            for (int q = 0; q < 4; ++q) {
                f32x4 bq = *reinterpret_cast<const f32x4*>(bias + i * 32 + q * 8 + h * 4);
                acc[q * 4 + 0] = bq[0]; acc[q * 4 + 1] = bq[1];
                acc[q * 4 + 2] = bq[2]; acc[q * 4 + 3] = bq[3];
            }
            acc = __builtin_amdgcn_mfma_f32_32x32x16_bf16(wfr[il][0], ef0, acc, 0, 0, 0);
            acc = __builtin_amdgcn_mfma_f32_32x32x16_bf16(wfr[il][1], ef1, acc, 0, 0, 0);
            acc = __builtin_amdgcn_mfma_f32_32x32x16_bf16(wfr[il][2], ef2, acc, 0, 0, 0);
            acc = __builtin_amdgcn_mfma_f32_32x32x16_bf16(wfr[il][3], ef3, acc, 0, 0, 0);

            // relu + matvec, 4 independent partials (chain depth 4)
            float s0 = 0.f, s1 = 0.f, s2 = 0.f, s3 = 0.f;
#pragma unroll
            for (int rr = 0; rr < 4; ++rr) {
                s0 += fmaxf(acc[rr],      0.f) * n0[rr];
                s1 += fmaxf(acc[4 + rr],  0.f) * n1[rr];
                s2 += fmaxf(acc[8 + rr],  0.f) * n2[rr];
                s3 += fmaxf(acc[12 + rr], 0.f) * n3[rr];
            }
            float p = (s0 + s1) + (s2 + s3);
            p += __shfl_xor(p, 32);           // add partner half's 16 j's
            vq[il] = p;
        }
        // store msg[eb+eg*32+l, 2*wid .. +1] (8 B per lane<32; L2 merges lines)
        if (l < 32)
            *reinterpret_cast<f32x2*>(out + (size_t)(eb + eg * 32 + l) * NODE_DIM
                                      + wid * 2) = vq;
    }
}

extern "C" void kernel_launch(void* const* d_in, const int* in_sizes, int n_in,
                              void* d_out, int out_size, void* d_ws, size_t ws_size,
                              hipStream_t stream) {
    const float* node = (const float*)d_in[0];  // [16,4096,32] f32
    const float* edge = (const float*)d_in[1];  // [16,4096,64] f32
    const float* W    = (const float*)d_in[2];  // [64,1024] f32
    const float* bias = (const float*)d_in[3];  // [1024] f32
    float* out = (float*)d_out;                 // [16,4096,32] f32
    short* Wb = (short*)d_ws;                   // 128 KB bf16 fragment-packed W

    prep_W<<<dim3(128), dim3(64), 0, stream>>>(W, Wb);
    mp_main<<<dim3(NROWS / 256), dim3(1024), 0, stream>>>(node, edge, Wb, bias, out);
}

// Round 11
// 29.848 us; speedup vs baseline: 1.3997x; 1.3997x over previous
//
#include <hip/hip_runtime.h>
#include <hip/hip_bf16.h>

typedef __attribute__((ext_vector_type(8))) short short8;
typedef __attribute__((ext_vector_type(4))) float f32x4;
typedef __attribute__((ext_vector_type(16))) float f32x16;
typedef unsigned int u32;

#define NROWS 65536             // BATCH * N_EDGES
#define EDGE_DIM 64
#define NODE_DIM 32
#define NN 1024                 // NODE_DIM^2

__device__ __forceinline__ short f2bf(float f) {
    unsigned u = __builtin_bit_cast(unsigned, f);
    u += 0x7FFFu + ((u >> 16) & 1u);            // round-to-nearest-even
    return (short)(u >> 16);
}

// async 16B global->LDS copy (dest = wave-uniform base + lane*16)
__device__ __forceinline__ void gload_lds16(const void* g, void* l) {
    __builtin_amdgcn_global_load_lds(
        (const __attribute__((address_space(1))) u32*)g,
        (__attribute__((address_space(3))) u32*)l, 16, 0, 0);
}

// Pack W [64,1024] f32 -> bf16 A-operand fragments for mfma_f32_32x32x16_bf16.
// frag id = i*4 + ks (i = output row 0..31, ks = K-step 0..3).
// Wb[(frag*64 + l)*8 + t] = bf16(W[ks*16 + (l>>5)*8 + t, i*32 + (l&31)])
// (verified correct R2..R10)
__global__ void prep_W(const float* __restrict__ W, short* __restrict__ Wb) {
    int frag = blockIdx.x;            // 128 blocks x 1 wave
    int l = threadIdx.x;              // 0..63
    int col = (frag >> 2) * 32 + (l & 31);
    int fb = (frag & 3) * 16 + ((l >> 5) * 8);
    short8 v;
#pragma unroll
    for (int t = 0; t < 8; ++t)
        v[t] = f2bf(W[(size_t)(fb + t) * NN + col]);
    *reinterpret_cast<short8*>(Wb + ((size_t)frag * 64 + l) * 8) = v;
}

// 256 blocks x 512 threads (8 waves) x 256 edges/block. Full packed W
// (128 KB) in LDS, staged once via global_load_lds (issued BEFORE the
// prologue so the L2 stream overlaps the edge/node loads); ONE barrier.
// Wave split = (eg, ihalf): wave handles 64 edges (2 MFMA col-groups
// sharing every W ds_read) x 16 i's -> DS reads 2/edge (half of R7),
// bias loads halved, all 64 lanes store 16B. launch_bounds(512,1):
// LDS caps at 1 block/CU anyway (2 waves/SIMD); no 128-VGPR cap ->
// no spill risk (R8-R10's hidden flaw). Barrier-free i-loop after stage.
__global__ __launch_bounds__(512, 1) void mp_main(
    const float* __restrict__ node, const float* __restrict__ edge,
    const short* __restrict__ Wb, const float* __restrict__ bias,
    float* __restrict__ out) {
    __shared__ __align__(16) short ldsW[65536];   // 128 KB: full packed W

    const int tid   = threadIdx.x;
    const int wid   = tid >> 6;               // 0..7
    const int l     = tid & 63;
    const int e32   = l & 31;                 // lane's edge col (MFMA N)
    const int h     = l >> 5;                 // lane half (k-group / row offset)
    const int eg    = wid & 3;                // 64-edge group
    const int ibase = (wid >> 2) * 16;        // i-half owned by this wave
    const int eb    = blockIdx.x * 256 + eg * 64;

    // ---- issue W staging FIRST: 16 x (512 lanes x 16 B) = 128 KB from L2
#pragma unroll
    for (int k = 0; k < 16; ++k)
        gload_lds16(Wb + (size_t)(k * 512 + tid) * 8,
                    &ldsW[(size_t)k * 4096 + wid * 512]);

    // ---- prologue (overlaps the staging stream) ----
    // ef[g][ks]: k = h*8+t -> edge[eb + g*32 + e32, ks*16 + h*8 + t]
    // nv[g][q*4+rr]: acc reg r=q*4+rr -> j = q*8 + h*4 + rr
    short8 ef[2][4];
    float  nv[2][16];
#pragma unroll
    for (int g = 0; g < 2; ++g) {
        const float* erow = edge + (size_t)(eb + g * 32 + e32) * EDGE_DIM;
#pragma unroll
        for (int ks = 0; ks < 4; ++ks) {
            f32x4 a = *reinterpret_cast<const f32x4*>(erow + ks * 16 + h * 8);
            f32x4 b = *reinterpret_cast<const f32x4*>(erow + ks * 16 + h * 8 + 4);
            short8 v;
            v[0] = f2bf(a[0]); v[1] = f2bf(a[1]); v[2] = f2bf(a[2]); v[3] = f2bf(a[3]);
            v[4] = f2bf(b[0]); v[5] = f2bf(b[1]); v[6] = f2bf(b[2]); v[7] = f2bf(b[3]);
            ef[g][ks] = v;
        }
        const float* nrow = node + (size_t)(eb + g * 32 + e32) * NODE_DIM;
#pragma unroll
        for (int q = 0; q < 4; ++q) {
            f32x4 n = *reinterpret_cast<const f32x4*>(nrow + q * 8 + h * 4);
            nv[g][q * 4 + 0] = n[0]; nv[g][q * 4 + 1] = n[1];
            nv[g][q * 4 + 2] = n[2]; nv[g][q * 4 + 3] = n[3];
        }
    }

    __syncthreads();                          // the ONLY barrier

    // lane's output row: all 64 lanes store (h picks the edge group)
    float* orow = out + (size_t)(eb + h * 32 + e32) * NODE_DIM + ibase;

#pragma unroll 2
    for (int iq = 0; iq < 4; ++iq) {
        f32x4 vq;
#pragma unroll
        for (int r = 0; r < 4; ++r) {
            const int i = ibase + iq * 4 + r;
            const short* wp = &ldsW[(size_t)i * 2048 + l * 8];
            short8 w0 = *reinterpret_cast<const short8*>(wp + 0 * 512);
            short8 w1 = *reinterpret_cast<const short8*>(wp + 1 * 512);
            short8 w2 = *reinterpret_cast<const short8*>(wp + 2 * 512);
            short8 w3 = *reinterpret_cast<const short8*>(wp + 3 * 512);

            // bias as C-init (same for both groups): reg q*4+rr -> row q*8+h*4+rr
            f32x16 acc0, acc1;
#pragma unroll
            for (int q = 0; q < 4; ++q) {
                f32x4 bq = *reinterpret_cast<const f32x4*>(bias + i * 32 + q * 8 + h * 4);
                acc0[q * 4 + 0] = bq[0]; acc0[q * 4 + 1] = bq[1];
                acc0[q * 4 + 2] = bq[2]; acc0[q * 4 + 3] = bq[3];
            }
            acc1 = acc0;

            acc0 = __builtin_amdgcn_mfma_f32_32x32x16_bf16(w0, ef[0][0], acc0, 0, 0, 0);
            acc1 = __builtin_amdgcn_mfma_f32_32x32x16_bf16(w0, ef[1][0], acc1, 0, 0, 0);
            acc0 = __builtin_amdgcn_mfma_f32_32x32x16_bf16(w1, ef[0][1], acc0, 0, 0, 0);
            acc1 = __builtin_amdgcn_mfma_f32_32x32x16_bf16(w1, ef[1][1], acc1, 0, 0, 0);
            acc0 = __builtin_amdgcn_mfma_f32_32x32x16_bf16(w2, ef[0][2], acc0, 0, 0, 0);
            acc1 = __builtin_amdgcn_mfma_f32_32x32x16_bf16(w2, ef[1][2], acc1, 0, 0, 0);
            acc0 = __builtin_amdgcn_mfma_f32_32x32x16_bf16(w3, ef[0][3], acc0, 0, 0, 0);
            acc1 = __builtin_amdgcn_mfma_f32_32x32x16_bf16(w3, ef[1][3], acc1, 0, 0, 0);

            // relu + matvec, 4 independent partials per group (chain depth 4)
            float s00 = 0.f, s01 = 0.f, s02 = 0.f, s03 = 0.f;
            float s10 = 0.f, s11 = 0.f, s12 = 0.f, s13 = 0.f;
#pragma unroll
            for (int rr = 0; rr < 4; ++rr) {
                s00 += fmaxf(acc0[rr],      0.f) * nv[0][rr];
                s01 += fmaxf(acc0[4 + rr],  0.f) * nv[0][4 + rr];
                s02 += fmaxf(acc0[8 + rr],  0.f) * nv[0][8 + rr];
                s03 += fmaxf(acc0[12 + rr], 0.f) * nv[0][12 + rr];
                s10 += fmaxf(acc1[rr],      0.f) * nv[1][rr];
                s11 += fmaxf(acc1[4 + rr],  0.f) * nv[1][4 + rr];
                s12 += fmaxf(acc1[8 + rr],  0.f) * nv[1][8 + rr];
                s13 += fmaxf(acc1[12 + rr], 0.f) * nv[1][12 + rr];
            }
            float p0 = (s00 + s01) + (s02 + s03);
            float p1 = (s10 + s11) + (s12 + s13);
            p0 += __shfl_xor(p0, 32);         // full j-sum, valid in all lanes
            p1 += __shfl_xor(p1, 32);
            vq[r] = h ? p1 : p0;              // lane's edge = eb + h*32 + e32
        }
        *reinterpret_cast<f32x4*>(orow + iq * 4) = vq;  // msg[e, ibase+iq*4..]
    }
}

extern "C" void kernel_launch(void* const* d_in, const int* in_sizes, int n_in,
                              void* d_out, int out_size, void* d_ws, size_t ws_size,
                              hipStream_t stream) {
    const float* node = (const float*)d_in[0];  // [16,4096,32] f32
    const float* edge = (const float*)d_in[1];  // [16,4096,64] f32
    const float* W    = (const float*)d_in[2];  // [64,1024] f32
    const float* bias = (const float*)d_in[3];  // [1024] f32
    float* out = (float*)d_out;                 // [16,4096,32] f32
    short* Wb = (short*)d_ws;                   // 128 KB bf16 fragment-packed W

    prep_W<<<dim3(128), dim3(64), 0, stream>>>(W, Wb);
    mp_main<<<dim3(NROWS / 256), dim3(512), 0, stream>>>(node, edge, Wb, bias, out);
}

// Round 12
// 23.827 us; speedup vs baseline: 1.7534x; 1.2527x over previous
//
#include <hip/hip_runtime.h>
#include <hip/hip_bf16.h>

typedef __attribute__((ext_vector_type(8))) short short8;
typedef __attribute__((ext_vector_type(4))) float f32x4;
typedef __attribute__((ext_vector_type(16))) float f32x16;

#define NROWS 65536             // BATCH * N_EDGES
#define EDGE_DIM 64
#define NODE_DIM 32
#define NN 1024                 // NODE_DIM^2

__device__ __forceinline__ short f2bf(float f) {
    unsigned u = __builtin_bit_cast(unsigned, f);
    u += 0x7FFFu + ((u >> 16) & 1u);            // round-to-nearest-even
    return (short)(u >> 16);
}

// SINGLE fused kernel (R12): R7's proven body (best K measured) with the W
// pre-pack pulled INTO the block — saves the prep_W dispatch + inter-kernel
// serialization (per-node graph overhead). 256 blocks x 512 threads (8 waves
// x 32 edges). Each block packs full W [64,1024] f32 -> bf16 MFMA fragments
// in its 128 KB LDS: per wave 16 frags, per frag 8 coalesced column loads
// (W f32 is 256 KB, L2/L3-hot across blocks+replays) + 1 conflict-free
// ds_write_b128 per lane. One barrier; then R7's barrier-free i-loop:
// 4 ds_read_b128 + bias C-init (L1-hot) + 4-chain mfma_32x32x16 +
// relu/matvec epilogue (4 indep partials) + shfl_xor(32) + f32x4 stores.
// Fragment layout (verified R2..R11): frag = i*4+ks;
// ldsW[(frag*64+l)*8+t] = bf16(W[ks*16 + (l>>5)*8 + t, i*32 + (l&31)]).
// No launch_bounds min-occupancy arg: LDS caps at 1 block/CU (2 waves/SIMD);
// an explicit VGPR cap was R8/R10's spill trap.
__global__ __launch_bounds__(512) void mp_fused(
    const float* __restrict__ node, const float* __restrict__ edge,
    const float* __restrict__ W, const float* __restrict__ bias,
    float* __restrict__ out) {
    __shared__ __align__(16) short ldsW[65536];   // 128 KB: full packed W

    const int tid = threadIdx.x;
    const int wid = tid >> 6;                 // 0..7
    const int l   = tid & 63;
    const int e32 = l & 31;                   // lane's edge col (MFMA N)
    const int h   = l >> 5;                   // lane half (k-group / row offset)
    const int eb  = blockIdx.x * 256 + wid * 32;
    const int e   = eb + e32;

    // ---- in-block W pack: wave wid packs frags [wid*16, wid*16+16) ----
#pragma unroll
    for (int m = 0; m < 16; ++m) {
        const int frag = wid * 16 + m;        // frag = i*4 + ks
        const int i  = frag >> 2;
        const int ks = frag & 3;
        const float* wp = W + (size_t)(ks * 16 + h * 8) * NN + i * 32 + e32;
        short8 v;
#pragma unroll
        for (int t = 0; t < 8; ++t)
            v[t] = f2bf(wp[(size_t)t * NN]);  // coalesced across lanes per t
        *reinterpret_cast<short8*>(&ldsW[((size_t)frag * 64 + l) * 8]) = v;
    }

    // ---- per-lane inputs (overlap the pack's VMEM stream) ----
    // ef[ks]: k = h*8+t -> edge[e, ks*16 + h*8 + t]
    // nv[q*4+rr]: acc reg r=q*4+rr -> j = q*8 + h*4 + rr
    short8 ef[4];
    float  nv[16];
    const float* erow = edge + (size_t)e * EDGE_DIM;
#pragma unroll
    for (int ks = 0; ks < 4; ++ks) {
        f32x4 a = *reinterpret_cast<const f32x4*>(erow + ks * 16 + h * 8);
        f32x4 b = *reinterpret_cast<const f32x4*>(erow + ks * 16 + h * 8 + 4);
        short8 v;
        v[0] = f2bf(a[0]); v[1] = f2bf(a[1]); v[2] = f2bf(a[2]); v[3] = f2bf(a[3]);
        v[4] = f2bf(b[0]); v[5] = f2bf(b[1]); v[6] = f2bf(b[2]); v[7] = f2bf(b[3]);
        ef[ks] = v;
    }
    const float* nrow = node + (size_t)e * NODE_DIM;
#pragma unroll
    for (int q = 0; q < 4; ++q) {
        f32x4 n = *reinterpret_cast<const f32x4*>(nrow + q * 8 + h * 4);
        nv[q * 4 + 0] = n[0]; nv[q * 4 + 1] = n[1];
        nv[q * 4 + 2] = n[2]; nv[q * 4 + 3] = n[3];
    }

    __syncthreads();                          // the ONLY barrier

    float* orow = out + (size_t)(eb + (l & 31)) * NODE_DIM;

#pragma unroll 2
    for (int iq = 0; iq < 8; ++iq) {
        f32x4 vq;
#pragma unroll
        for (int r = 0; r < 4; ++r) {
            const int i = iq * 4 + r;
            const short* wp = &ldsW[(size_t)i * 2048 + l * 8];
            short8 w0 = *reinterpret_cast<const short8*>(wp + 0 * 512);
            short8 w1 = *reinterpret_cast<const short8*>(wp + 1 * 512);
            short8 w2 = *reinterpret_cast<const short8*>(wp + 2 * 512);
            short8 w3 = *reinterpret_cast<const short8*>(wp + 3 * 512);

            // bias as C-init: reg q*4+rr -> row q*8 + h*4 + rr (L1-hot)
            f32x16 acc;
#pragma unroll
            for (int q = 0; q < 4; ++q) {
                f32x4 bq = *reinterpret_cast<const f32x4*>(bias + i * 32 + q * 8 + h * 4);
                acc[q * 4 + 0] = bq[0]; acc[q * 4 + 1] = bq[1];
                acc[q * 4 + 2] = bq[2]; acc[q * 4 + 3] = bq[3];
            }

            acc = __builtin_amdgcn_mfma_f32_32x32x16_bf16(w0, ef[0], acc, 0, 0, 0);
            acc = __builtin_amdgcn_mfma_f32_32x32x16_bf16(w1, ef[1], acc, 0, 0, 0);
            acc = __builtin_amdgcn_mfma_f32_32x32x16_bf16(w2, ef[2], acc, 0, 0, 0);
            acc = __builtin_amdgcn_mfma_f32_32x32x16_bf16(w3, ef[3], acc, 0, 0, 0);

            // relu + matvec, 4 independent partials (chain depth 4)
            float s0 = 0.f, s1 = 0.f, s2 = 0.f, s3 = 0.f;
#pragma unroll
            for (int rr = 0; rr < 4; ++rr) {
                s0 += fmaxf(acc[rr],      0.f) * nv[rr];
                s1 += fmaxf(acc[4 + rr],  0.f) * nv[4 + rr];
                s2 += fmaxf(acc[8 + rr],  0.f) * nv[8 + rr];
                s3 += fmaxf(acc[12 + rr], 0.f) * nv[12 + rr];
            }
            float p = (s0 + s1) + (s2 + s3);
            p += __shfl_xor(p, 32);           // add partner half's 16 j's
            vq[r] = p;
        }
        if (l < 32)
            *reinterpret_cast<f32x4*>(orow + iq * 4) = vq;  // msg[e, iq*4..+3]
    }
}

extern "C" void kernel_launch(void* const* d_in, const int* in_sizes, int n_in,
                              void* d_out, int out_size, void* d_ws, size_t ws_size,
                              hipStream_t stream) {
    const float* node = (const float*)d_in[0];  // [16,4096,32] f32
    const float* edge = (const float*)d_in[1];  // [16,4096,64] f32
    const float* W    = (const float*)d_in[2];  // [64,1024] f32
    const float* bias = (const float*)d_in[3];  // [1024] f32
    float* out = (float*)d_out;                 // [16,4096,32] f32

    mp_fused<<<dim3(NROWS / 256), dim3(512), 0, stream>>>(node, edge, W, bias, out);
}